// Round 4
// baseline (251.521 us; speedup 1.0000x reference)
//
#include <hip/hip_runtime.h>

// Conv 3x3 VALID, NCHW/OIHW, fp32. x=[64,3,224,224], w=[16,3,3,3] -> out=[64,16,222,222].
// R4: dense-store layout. One wave = one output row; slots phased per row parity so
// every store is an aligned float4 (one float2 edge per row). nt stores, scalar filters.

namespace {
constexpr int B  = 64, C = 3, H = 224, W = 224;
constexpr int OC = 16, KS = 3, OH = 222, OW = 222;
constexpr int BLOCK = 256;
constexpr int RPB   = 4;                  // rows per block (1 per wave)
constexpr int NOG   = (OH + RPB - 1) / RPB;   // 56 row groups
constexpr int GRID  = B * NOG;            // 3584 blocks
typedef float f32x2 __attribute__((ext_vector_type(2)));
typedef float f32x4 __attribute__((ext_vector_type(4)));
}

__global__ __launch_bounds__(BLOCK, 4) void conv3x3_kernel(
    const float* __restrict__ x, const float* __restrict__ flt,
    float* __restrict__ out) {
  const int wid  = threadIdx.x >> 6;
  const int lane = threadIdx.x & 63;
  const int bb   = blockIdx.x / NOG;
  const int og   = blockIdx.x % NOG;
  const int oh   = og * RPB + wid;
  if (oh >= OH) return;                       // wave-uniform exit (last group only)

  const bool odd = (oh & 1) != 0;
  const int  s      = lane < 56 ? lane : 55;  // slot; lanes 56-63 shadow slot 55
  const bool active = lane < 56;
  const bool l0  = odd && (s == 0);           // odd-row left edge: float2 @ ow 0
  const bool e55 = !odd && (s == 55);         // even-row right edge: float2 @ ow 220
  // Output group start (may be -2 for l0; only j=2,3 valid there).
  const int ow0 = odd ? 4 * s - 2 : 4 * s;
  // Aligned load columns. Window [la, la+8) covers all taps of this slot's outputs.
  const int la = odd ? (s == 0 ? 0 : 4 * s - 4) : (s == 55 ? 220 : 4 * s);
  const int lb = e55 ? la : la + 4;           // dup for e55 (avoids [224,228) OOB)

  // 9 x 8-wide register windows, then normalize so w[q] = input col (ow0 + q).
  float c8[C * KS][8];
  const float* xb = x + (size_t)bb * (C * H * W);
#pragma unroll
  for (int c = 0; c < C; ++c) {
#pragma unroll
    for (int r = 0; r < KS; ++r) {
      const float* row = xb + (c * H + oh + r) * W;
      const f32x4 a  = *reinterpret_cast<const f32x4*>(row + la);
      const f32x4 bv = *reinterpret_cast<const f32x4*>(row + lb);
      float* w = c8[c * KS + r];
      w[0] = a.x;  w[1] = a.y;  w[2] = a.z;  w[3] = a.w;
      w[4] = bv.x; w[5] = bv.y; w[6] = bv.z; w[7] = bv.w;
      if (odd) {  // wave-uniform branch; shift window left 2 (l0: right 2)
        const float t0 = w[0], t1 = w[1], t2 = w[2], t3 = w[3];
        w[0] = l0 ? t0 : w[2];   // l0's w[0],w[1] are unused garbage (finite)
        w[1] = l0 ? t1 : w[3];
        w[2] = l0 ? t0 : w[4];   // l0: col 0
        w[3] = l0 ? t1 : w[5];   // l0: col 1
        w[4] = l0 ? t2 : w[6];
        w[5] = l0 ? t3 : w[7];
      }
    }
  }

  const size_t ocs = (size_t)OH * OW;
  float* op0 = out + (size_t)bb * OC * ocs + (size_t)oh * OW;
#pragma unroll 1
  for (int oc = 0; oc < OC; ++oc) {
    float fv[27];   // wave-uniform -> s_load / SGPR operands to v_fmac
#pragma unroll
    for (int k = 0; k < 27; ++k) fv[k] = flt[oc * 27 + k];

    float a0 = 0.f, a1 = 0.f, a2 = 0.f, a3 = 0.f;
#pragma unroll
    for (int c = 0; c < C; ++c)
#pragma unroll
      for (int r = 0; r < KS; ++r) {
        const float* w = c8[c * KS + r];
#pragma unroll
        for (int kw = 0; kw < KS; ++kw) {
          const float f = fv[c * 9 + r * 3 + kw];
          a0 = fmaf(f, w[kw + 0], a0);
          a1 = fmaf(f, w[kw + 1], a1);
          a2 = fmaf(f, w[kw + 2], a2);
          a3 = fmaf(f, w[kw + 3], a3);
        }
      }

    if (active) {
      float* op = op0 + (size_t)oc * ocs;
      if (l0) {               // ow 0,1 are acc j=2,3 (ow0 == -2)
        f32x2 v; v.x = a2; v.y = a3;
        __builtin_nontemporal_store(v, reinterpret_cast<f32x2*>(op));
      } else if (e55) {       // ow 220,221
        f32x2 v; v.x = a0; v.y = a1;
        __builtin_nontemporal_store(v, reinterpret_cast<f32x2*>(op + 220));
      } else {                // aligned dense float4
        f32x4 v; v.x = a0; v.y = a1; v.z = a2; v.w = a3;
        __builtin_nontemporal_store(v, reinterpret_cast<f32x4*>(op + ow0));
      }
    }
  }
}

extern "C" void kernel_launch(void* const* d_in, const int* in_sizes, int n_in,
                              void* d_out, int out_size, void* d_ws, size_t ws_size,
                              hipStream_t stream) {
  const float* x = (const float*)d_in[0];
  const float* f = (const float*)d_in[1];
  float* o       = (float*)d_out;
  conv3x3_kernel<<<GRID, BLOCK, 0, stream>>>(x, f, o);
}

// Round 5
// 236.021 us; speedup vs baseline: 1.0657x; 1.0657x over previous
//
#include <hip/hip_runtime.h>

// Conv 3x3 VALID, NCHW/OIHW, fp32. x=[64,3,224,224], w=[16,3,3,3] -> out=[64,16,222,222].
// R5 = R3 base (4 ow x 16 oc per thread, scalar filters, no LDS) with:
//  - plain stores (drop nontemporal: let L2 write-combine the float2 pairs to dense sectors)
//  - bijective XCD chunk swizzle (same-image blocks share one XCD's L2 for input reuse)

namespace {
constexpr int B  = 64, C = 3, H = 224, W = 224;
constexpr int OC = 16, KS = 3, OH = 222, OW = 222;
constexpr int NW4   = 56;               // ceil(OW/4)
constexpr int TOTAL = B * OH * NW4;     // 795,648 = 3108 * 256 exactly (no thread tail)
constexpr int BLOCK = 256;
constexpr int NWG   = TOTAL / BLOCK;    // 3108
constexpr int NXCD  = 8;
typedef float f32x2 __attribute__((ext_vector_type(2)));
}

__global__ __launch_bounds__(BLOCK, 4) void conv3x3_kernel(
    const float* __restrict__ x, const float* __restrict__ flt,
    float* __restrict__ out) {
  // Bijective XCD swizzle (m204 form): round-robin xcd assignment -> contiguous
  // per-XCD chunks, so adjacent output rows (sharing input rows) co-reside.
  const int orig = blockIdx.x;
  const int xcd  = orig % NXCD;
  const int idx  = orig / NXCD;
  constexpr int q = NWG / NXCD;          // 388
  constexpr int r = NWG % NXCD;          // 4
  const int wg = (xcd < r ? xcd * (q + 1) : r * (q + 1) + (xcd - r) * q) + idx;

  const int tid = wg * BLOCK + threadIdx.x;   // always < TOTAL (exact grid)
  const int g  = tid % NW4;
  const int t1 = tid / NW4;
  const int oh = t1 % OH;
  const int b  = t1 / OH;
  const int w0 = g * 4;
  const bool tail = (g == NW4 - 1);       // w0 == 220: only 2 valid outputs
  const int  wb   = tail ? w0 : w0 + 4;   // clamped second load (no OOB; duplicates cols)

  // 3x3 window over 8 input cols, 2 aligned float4 per (c,row) = 18 vec loads.
  float c8[C][KS][8];
  const float* xb = x + (size_t)b * (C * H * W);
#pragma unroll
  for (int c = 0; c < C; ++c) {
#pragma unroll
    for (int r2 = 0; r2 < KS; ++r2) {
      const float* row = xb + (c * H + oh + r2) * W;
      const float4 a  = *reinterpret_cast<const float4*>(row + w0);
      const float4 bb = *reinterpret_cast<const float4*>(row + wb);
      c8[c][r2][0] = a.x;  c8[c][r2][1] = a.y;  c8[c][r2][2] = a.z;  c8[c][r2][3] = a.w;
      c8[c][r2][4] = bb.x; c8[c][r2][5] = bb.y; c8[c][r2][6] = bb.z; c8[c][r2][7] = bb.w;
    }
  }

  float* outp = out + (size_t)(b * OC) * (OH * OW) + (size_t)oh * OW + w0;
#pragma unroll 1
  for (int oc = 0; oc < OC; ++oc) {
    // Wave-uniform index + uniform control flow -> s_load; SGPR operand to v_fmac.
    float fv[27];
#pragma unroll
    for (int k = 0; k < 27; ++k) fv[k] = flt[oc * 27 + k];

    float a0 = 0.f, a1 = 0.f, a2 = 0.f, a3 = 0.f;
#pragma unroll
    for (int c = 0; c < C; ++c)
#pragma unroll
      for (int r2 = 0; r2 < KS; ++r2)
#pragma unroll
        for (int kw = 0; kw < KS; ++kw) {
          const float wv = fv[c * 9 + r2 * 3 + kw];
          a0 = fmaf(wv, c8[c][r2][kw + 0], a0);
          a1 = fmaf(wv, c8[c][r2][kw + 1], a1);
          a2 = fmaf(wv, c8[c][r2][kw + 2], a2);
          a3 = fmaf(wv, c8[c][r2][kw + 3], a3);
        }

    // Output row stride = 888 B (8B-aligned only) -> float2 stores, plain
    // (write-allocate): L2 merges the lane-interleaved pairs into dense sectors.
    float* op = outp + (size_t)oc * (OH * OW);
    if (!tail) {
      *reinterpret_cast<f32x2*>(op + 0) = f32x2{a0, a1};
      *reinterpret_cast<f32x2*>(op + 2) = f32x2{a2, a3};
    } else {
      op[0] = a0;   // ow = 220
      op[1] = a1;   // ow = 221
    }
  }
}

extern "C" void kernel_launch(void* const* d_in, const int* in_sizes, int n_in,
                              void* d_out, int out_size, void* d_ws, size_t ws_size,
                              hipStream_t stream) {
  const float* x = (const float*)d_in[0];
  const float* f = (const float*)d_in[1];
  float* o       = (float*)d_out;
  conv3x3_kernel<<<NWG, BLOCK, 0, stream>>>(x, f, o);
}

// Round 6
// 235.051 us; speedup vs baseline: 1.0701x; 1.0041x over previous
//
#include <hip/hip_runtime.h>

// Conv 3x3 VALID, NCHW/OIHW, fp32. x=[64,3,224,224], w=[16,3,3,3] -> out=[64,16,222,222].
// R6 = R5 + oh-pairing: each thread does 4 ow x 2 oh x 16 oc. Input rows 4 (not 6)
// per pair, filter s_loads amortized over 8 outputs. Plain f32x2 stores, XCD swizzle.

namespace {
constexpr int B  = 64, C = 3, H = 224, W = 224;
constexpr int OC = 16, KS = 3, OH = 222, OW = 222;
constexpr int NW4   = 56;                 // ceil(OW/4)
constexpr int OHP   = OH / 2;             // 111 row pairs
constexpr int TOTAL = B * OHP * NW4;      // 397,824 = 1554 * 256 exactly
constexpr int BLOCK = 256;
constexpr int NWG   = TOTAL / BLOCK;      // 1554
constexpr int NXCD  = 8;
typedef float f32x2 __attribute__((ext_vector_type(2)));
}

__global__ __launch_bounds__(BLOCK, 3) void conv3x3_kernel(
    const float* __restrict__ x, const float* __restrict__ flt,
    float* __restrict__ out) {
  // Bijective XCD chunk swizzle (nwg % 8 != 0 safe).
  const int orig = blockIdx.x;
  const int xcd  = orig % NXCD;
  const int idx  = orig / NXCD;
  constexpr int q = NWG / NXCD;           // 194
  constexpr int r = NWG % NXCD;           // 2
  const int wg = (xcd < r ? xcd * (q + 1) : r * (q + 1) + (xcd - r) * q) + idx;

  const int tid = wg * BLOCK + threadIdx.x;   // < TOTAL (exact grid)
  const int g   = tid % NW4;
  const int t1  = tid / NW4;
  const int hp  = t1 % OHP;
  const int b   = t1 / OHP;
  const int oh0 = hp * 2;
  const int w0  = g * 4;
  const bool tail = (g == NW4 - 1);        // w0 == 220: 2 valid outputs per row
  const int  wb   = tail ? w0 : w0 + 4;    // clamped second load (no OOB)

  // 4 input rows x 3 channels, 8 cols each: 24 aligned float4 loads.
  float c8[C][4][8];
  const float* xb = x + (size_t)b * (C * H * W);
#pragma unroll
  for (int c = 0; c < C; ++c) {
#pragma unroll
    for (int r2 = 0; r2 < 4; ++r2) {
      const float* row = xb + (c * H + oh0 + r2) * W;
      const float4 a  = *reinterpret_cast<const float4*>(row + w0);
      const float4 bb = *reinterpret_cast<const float4*>(row + wb);
      c8[c][r2][0] = a.x;  c8[c][r2][1] = a.y;  c8[c][r2][2] = a.z;  c8[c][r2][3] = a.w;
      c8[c][r2][4] = bb.x; c8[c][r2][5] = bb.y; c8[c][r2][6] = bb.z; c8[c][r2][7] = bb.w;
    }
  }

  const size_t ocs = (size_t)OH * OW;
  float* outA = out + (size_t)(b * OC) * ocs + (size_t)oh0 * OW + w0;
#pragma unroll 1
  for (int oc = 0; oc < OC; ++oc) {
    // Wave-uniform filter reads -> s_load; SGPR operand to v_fmac.
    float fv[27];
#pragma unroll
    for (int k = 0; k < 27; ++k) fv[k] = flt[oc * 27 + k];

    float a0 = 0.f, a1 = 0.f, a2 = 0.f, a3 = 0.f;   // out row oh0
    float b0 = 0.f, b1 = 0.f, b2 = 0.f, b3 = 0.f;   // out row oh0+1
#pragma unroll
    for (int c = 0; c < C; ++c)
#pragma unroll
      for (int kr = 0; kr < KS; ++kr) {
        const float* wA = c8[c][kr];       // taps for out row oh0
        const float* wB = c8[c][kr + 1];   // taps for out row oh0+1
#pragma unroll
        for (int kw = 0; kw < KS; ++kw) {
          const float f = fv[c * 9 + kr * 3 + kw];
          a0 = fmaf(f, wA[kw + 0], a0);
          a1 = fmaf(f, wA[kw + 1], a1);
          a2 = fmaf(f, wA[kw + 2], a2);
          a3 = fmaf(f, wA[kw + 3], a3);
          b0 = fmaf(f, wB[kw + 0], b0);
          b1 = fmaf(f, wB[kw + 1], b1);
          b2 = fmaf(f, wB[kw + 2], b2);
          b3 = fmaf(f, wB[kw + 3], b3);
        }
      }

    // Row stride 888 B (8B-aligned) -> f32x2 stores; L2 merges to dense sectors.
    float* opA = outA + (size_t)oc * ocs;
    float* opB = opA + OW;
    if (!tail) {
      *reinterpret_cast<f32x2*>(opA + 0) = f32x2{a0, a1};
      *reinterpret_cast<f32x2*>(opA + 2) = f32x2{a2, a3};
      *reinterpret_cast<f32x2*>(opB + 0) = f32x2{b0, b1};
      *reinterpret_cast<f32x2*>(opB + 2) = f32x2{b2, b3};
    } else {
      opA[0] = a0; opA[1] = a1;   // ow 220,221
      opB[0] = b0; opB[1] = b1;
    }
  }
}

extern "C" void kernel_launch(void* const* d_in, const int* in_sizes, int n_in,
                              void* d_out, int out_size, void* d_ws, size_t ws_size,
                              hipStream_t stream) {
  const float* x = (const float*)d_in[0];
  const float* f = (const float*)d_in[1];
  float* o       = (float*)d_out;
  conv3x3_kernel<<<NWG, BLOCK, 0, stream>>>(x, f, o);
}